// Round 15
// baseline (136.252 us; speedup 1.0000x reference)
//
#include <hip/hip_runtime.h>
#include <math.h>

// n=1024, raw=128, d=128, h=256
// prep (257 blocks): blocks 0..255: z = x@W_enc + b_enc (LDS);
//   a' = (z@W1[:d])*log2e; b' = (z@W1[d:]+b1)*log2e; e=exp2(a'), f=exp2(b')
//   f16 half2 planes [k2][n] (k-paired via shfl_xor(1)):
//     PAa=half2{a'/64}, PAe=half2{e}, PBb=half2{b'/64}, PBe=half2{f}.
//   (1/64 prescale => |t'|/64 < 1, so max(t',0)/64 == clamp(a/64+b/64);
//    e*f>=0 so min(e*f,1)==clamp(e*f). VOP3P clamp bit fuses both.)
//   block 256: base = b2 - SELU_AS*sum(W2);
//     W2m[k2]=half2{64*S_OVER_L2E*w}, W2e[k2]=half2{SELU_AS*w}
// pair (grid 256, 512 thr): XCD-swizzled 64x64 tile. Wave w = K-eighth,
//   k2 in [16w,16w+16), 2 sub-chunks of 8 k2 in a WAVE-PRIVATE 8 KB LDS
//   region (no staging barriers); sub-chunk 1's global loads are issued
//   BEFORE hot loop 0 (latency hidden behind ~4096 VALU instr).
//   Hot loop: 4 instr/pair-k2: pk_add+clamp, pk_mul+clamp, 2x fdot2.
//   3-round LDS tree-reduction over K-eighths; wave 0 writes hsig.

#define LOG2E       1.4426950408889634f
#define SELU_AS     1.7580993408473766f   // scale*alpha
#define S_OVER_L2E  0.7282921587620419f   // scale/log2e
#define INV64       0.015625f

typedef float v2f __attribute__((ext_vector_type(2)));
typedef _Float16 v2h __attribute__((ext_vector_type(2)));
typedef unsigned int u32;

__global__ __launch_bounds__(256) void prep_kernel(
    const float* __restrict__ x, const float* __restrict__ W_enc,
    const float* __restrict__ b_enc, const float* __restrict__ W1,
    const float* __restrict__ b1, const float* __restrict__ W2,
    const float* __restrict__ b2, u32* __restrict__ PAa,
    u32* __restrict__ PAe, u32* __restrict__ PBb, u32* __restrict__ PBe,
    u32* __restrict__ W2m, u32* __restrict__ W2e, float* __restrict__ basep)
{
    __shared__ float zs[512];
    int t = threadIdx.x, b = blockIdx.x;
    if (b < 256) {
        int r0 = b << 2;
        int r = t >> 6;                   // wave-uniform row 0..3
        int dd = (t & 63) << 1;
        const float* xr = x + (size_t)(r0 + r) * 128;
        v2f z = { b_enc[dd], b_enc[dd + 1] };
#pragma unroll 8
        for (int dl = 0; dl < 128; ++dl) {
            float xv = xr[dl];
            v2f xx = { xv, xv };
            v2f wv = *(const v2f*)(W_enc + (size_t)dl * 128 + dd);
            z = __builtin_elementwise_fma(xx, wv, z);
        }
        zs[r * 128 + dd] = z.x;
        zs[r * 128 + dd + 1] = z.y;
        __syncthreads();

        int c = t;                        // h-column (= k) 0..255
        float b1c = b1[c];
        float accA0 = 0.f, accA1 = 0.f, accA2 = 0.f, accA3 = 0.f;
        float accB0 = b1c, accB1 = b1c, accB2 = b1c, accB3 = b1c;
        const float* w1a = W1 + c;
        const float* w1b = W1 + 128 * 256 + c;
#pragma unroll 4
        for (int dl = 0; dl < 128; ++dl) {
            float wa = w1a[(size_t)dl * 256];
            float wb = w1b[(size_t)dl * 256];
            float z0 = zs[dl], z1 = zs[128 + dl], z2 = zs[256 + dl], z3 = zs[384 + dl];
            accA0 = fmaf(z0, wa, accA0); accB0 = fmaf(z0, wb, accB0);
            accA1 = fmaf(z1, wa, accA1); accB1 = fmaf(z1, wb, accB1);
            accA2 = fmaf(z2, wa, accA2); accB2 = fmaf(z2, wb, accB2);
            accA3 = fmaf(z3, wa, accA3); accB3 = fmaf(z3, wb, accB3);
        }
        float ar[4] = { accA0 * LOG2E, accA1 * LOG2E, accA2 * LOG2E, accA3 * LOG2E };
        float br[4] = { accB0 * LOG2E, accB1 * LOG2E, accB2 * LOG2E, accB3 * LOG2E };
        u32 pa[4], pe[4], pb[4], pf[4];
        bool odd = (c & 1);
#pragma unroll
        for (int r2 = 0; r2 < 4; ++r2) {
            float er = __builtin_amdgcn_exp2f(ar[r2]);
            float fr = __builtin_amdgcn_exp2f(br[r2]);
            float aN = __shfl_xor(ar[r2], 1);
            float eN = __shfl_xor(er, 1);
            float bN = __shfl_xor(br[r2], 1);
            float fN = __shfl_xor(fr, 1);
            pa[r2] = __builtin_bit_cast(u32,
                __builtin_amdgcn_cvt_pkrtz(ar[r2] * INV64, aN * INV64));
            pe[r2] = __builtin_bit_cast(u32, __builtin_amdgcn_cvt_pkrtz(er, eN));
            pb[r2] = __builtin_bit_cast(u32,
                __builtin_amdgcn_cvt_pkrtz(bN * INV64, br[r2] * INV64));
            pf[r2] = __builtin_bit_cast(u32, __builtin_amdgcn_cvt_pkrtz(fN, fr));
        }
        size_t o = (size_t)(c >> 1) * 1024 + r0;    // [k2][n]
        if (!odd) {
            *(uint4*)(PAa + o) = make_uint4(pa[0], pa[1], pa[2], pa[3]);
            *(uint4*)(PAe + o) = make_uint4(pe[0], pe[1], pe[2], pe[3]);
        } else {
            *(uint4*)(PBb + o) = make_uint4(pb[0], pb[1], pb[2], pb[3]);
            *(uint4*)(PBe + o) = make_uint4(pf[0], pf[1], pf[2], pf[3]);
        }
    } else {
        if (t < 128) {
            float w0 = W2[2 * t], w1 = W2[2 * t + 1];
            const float S64 = S_OVER_L2E * 64.0f;
            W2m[t] = __builtin_bit_cast(u32,
                __builtin_amdgcn_cvt_pkrtz(S64 * w0, S64 * w1));
            W2e[t] = __builtin_bit_cast(u32,
                __builtin_amdgcn_cvt_pkrtz(SELU_AS * w0, SELU_AS * w1));
        }
        if (t < 64) {
            float s = W2[t] + W2[t + 64] + W2[t + 128] + W2[t + 192];
#pragma unroll
            for (int o = 32; o > 0; o >>= 1) s += __shfl_down(s, o);
            if (t == 0) basep[0] = fmaf(-SELU_AS, s, b2[0]);
        }
    }
}

__device__ __forceinline__ v2h clamp2(v2h v) {
    const v2h z = { (_Float16)0.f, (_Float16)0.f };
    const v2h o = { (_Float16)1.f, (_Float16)1.f };
    // minnum(maxnum(x,0),1) -> VOP3P clamp bit on the producing instruction
    return __builtin_elementwise_min(__builtin_elementwise_max(v, z), o);
}

// grid 256 (1D, XCD-swizzled), 512 threads = 8 waves. Wave w covers k2 in
// [16w,16w+16) via 2 sub-chunks of 8 k2 in its PRIVATE 8 KB LDS region.
// Sub-chunk 1 globals prefetched before hot loop 0. 8x8 tile/thread.
__global__ __launch_bounds__(512, 2) void pair_kernel(
    const u32* __restrict__ PAa, const u32* __restrict__ PAe,
    const u32* __restrict__ PBb, const u32* __restrict__ PBe,
    const u32* __restrict__ W2m, const u32* __restrict__ W2e,
    const float* __restrict__ basep, float* __restrict__ out)
{
    __shared__ __align__(16) u32 S[16384];   // 64 KB

    int t = threadIdx.x;
    int w = t >> 6;                 // wave / K-eighth 0..7
    int lt = t & 63;
    // XCD swizzle: dispatch maps b -> XCD b%8. Give XCD x a 2-row x 16-col
    // stripe of the 16x16 tile grid: its 32 blocks share 2 B-plane stripes.
    int b = blockIdx.x;
    int x8 = b & 7, q = b >> 3;               // q 0..31
    int bi_idx = (x8 << 1) + (q >> 4);        // 0..15
    int bj_idx = q & 15;                      // 0..15
    int bj64 = bj_idx << 6, bi64 = bi_idx << 6;
    int jb = (lt & 7) << 3;         // j base 0..56
    int ib = (lt >> 3) << 3;        // i base 0..56

    u32* Q  = S + (w << 11);        // 2048 u32 = 8 KB, wave-private
    u32* Aa = Q;                    // [8 k2][64]
    u32* Ae = Q + 512;
    u32* Bb = Q + 1024;
    u32* Be = Q + 1536;

    float acc[8][8];
#pragma unroll
    for (int i = 0; i < 8; ++i)
#pragma unroll
        for (int j = 0; j < 8; ++j) acc[i][j] = 0.f;

    const v2h hone = { (_Float16)1.f, (_Float16)1.f };

    // staging address helpers (lane-fixed parts)
    int s_row[2], s_col[2];
#pragma unroll
    for (int p = 0; p < 2; ++p) {
        int idx = (p << 6) + lt;             // 0..127
        s_row[p] = idx >> 4;                 // 0..7
        s_col[p] = (idx & 15) << 2;
    }

    // prefetch sub-chunk 0
    uint4 ga[2], ge[2], gb[2], gf[2];
    {
        int k2base = (w << 4);
#pragma unroll
        for (int p = 0; p < 2; ++p) {
            size_t go = (size_t)(k2base + s_row[p]) * 1024;
            ga[p] = *(const uint4*)(PAa + go + bj64 + s_col[p]);
            ge[p] = *(const uint4*)(PAe + go + bj64 + s_col[p]);
            gb[p] = *(const uint4*)(PBb + go + bi64 + s_col[p]);
            gf[p] = *(const uint4*)(PBe + go + bi64 + s_col[p]);
        }
    }

    for (int sc = 0; sc < 2; ++sc) {
        int k2base = (w << 4) + (sc << 3);
        asm volatile("" ::: "memory");       // keep stage writes after prior reads
        // write staged regs -> wave-private LDS
#pragma unroll
        for (int p = 0; p < 2; ++p) {
            int idx = (p << 6) + lt;
            *(uint4*)&Aa[idx << 2] = ga[p];
            *(uint4*)&Ae[idx << 2] = ge[p];
            *(uint4*)&Bb[idx << 2] = gb[p];
            *(uint4*)&Be[idx << 2] = gf[p];
        }
        // prefetch sub-chunk 1 globals while hot loop 0 runs
        if (sc == 0) {
            int k2n = (w << 4) + 8;
#pragma unroll
            for (int p = 0; p < 2; ++p) {
                size_t go = (size_t)(k2n + s_row[p]) * 1024;
                ga[p] = *(const uint4*)(PAa + go + bj64 + s_col[p]);
                ge[p] = *(const uint4*)(PAe + go + bj64 + s_col[p]);
                gb[p] = *(const uint4*)(PBb + go + bi64 + s_col[p]);
                gf[p] = *(const uint4*)(PBe + go + bi64 + s_col[p]);
            }
        }
        asm volatile("s_waitcnt lgkmcnt(0)" ::: "memory");  // wave-private: no barrier

        const u32* Wm = W2m + k2base;
        const u32* We = W2e + k2base;
#pragma unroll 4
        for (int k2 = 0; k2 < 8; ++k2) {
            v2h w2m = __builtin_bit_cast(v2h, Wm[k2]);       // uniform -> s_load
            v2h w2e = __builtin_bit_cast(v2h, We[k2]);
            uint4 qa0 = *(const uint4*)&Aa[(k2 << 6) + jb];
            uint4 qa1 = *(const uint4*)&Aa[(k2 << 6) + jb + 4];
            uint4 qe0 = *(const uint4*)&Ae[(k2 << 6) + jb];
            uint4 qe1 = *(const uint4*)&Ae[(k2 << 6) + jb + 4];
            uint4 qb0 = *(const uint4*)&Bb[(k2 << 6) + ib];
            uint4 qb1 = *(const uint4*)&Bb[(k2 << 6) + ib + 4];
            uint4 qf0 = *(const uint4*)&Be[(k2 << 6) + ib];
            uint4 qf1 = *(const uint4*)&Be[(k2 << 6) + ib + 4];
            v2h A[8] = { __builtin_bit_cast(v2h, qa0.x), __builtin_bit_cast(v2h, qa0.y),
                         __builtin_bit_cast(v2h, qa0.z), __builtin_bit_cast(v2h, qa0.w),
                         __builtin_bit_cast(v2h, qa1.x), __builtin_bit_cast(v2h, qa1.y),
                         __builtin_bit_cast(v2h, qa1.z), __builtin_bit_cast(v2h, qa1.w) };
            v2h E[8] = { __builtin_bit_cast(v2h, qe0.x), __builtin_bit_cast(v2h, qe0.y),
                         __builtin_bit_cast(v2h, qe0.z), __builtin_bit_cast(v2h, qe0.w),
                         __builtin_bit_cast(v2h, qe1.x), __builtin_bit_cast(v2h, qe1.y),
                         __builtin_bit_cast(v2h, qe1.z), __builtin_bit_cast(v2h, qe1.w) };
            v2h B[8] = { __builtin_bit_cast(v2h, qb0.x), __builtin_bit_cast(v2h, qb0.y),
                         __builtin_bit_cast(v2h, qb0.z), __builtin_bit_cast(v2h, qb0.w),
                         __builtin_bit_cast(v2h, qb1.x), __builtin_bit_cast(v2h, qb1.y),
                         __builtin_bit_cast(v2h, qb1.z), __builtin_bit_cast(v2h, qb1.w) };
            v2h F[8] = { __builtin_bit_cast(v2h, qf0.x), __builtin_bit_cast(v2h, qf0.y),
                         __builtin_bit_cast(v2h, qf0.z), __builtin_bit_cast(v2h, qf0.w),
                         __builtin_bit_cast(v2h, qf1.x), __builtin_bit_cast(v2h, qf1.y),
                         __builtin_bit_cast(v2h, qf1.z), __builtin_bit_cast(v2h, qf1.w) };
#pragma unroll
            for (int i = 0; i < 8; ++i) {
#pragma unroll
                for (int j = 0; j < 8; ++j) {
                    v2h t2 = clamp2(A[j] + B[i]);   // pk_add_f16 + clamp bit
                    v2h p2 = clamp2(E[j] * F[i]);   // pk_mul_f16 + clamp bit
                    acc[i][j] = __builtin_amdgcn_fdot2(t2, w2m, acc[i][j], false);
                    acc[i][j] = __builtin_amdgcn_fdot2(p2, w2e, acc[i][j], false);
                }
            }
        }
    }

    // ---- tree reduction over the 8 K-eighths (regions: 16 KB each) ----
    float4* buf = (float4*)S;
#define STORE_ACC(REG) {                                                  \
        float4* r_ = buf + ((REG) << 10);                                 \
        _Pragma("unroll")                                                 \
        for (int i = 0; i < 8; ++i) {                                     \
            float4 lo = { acc[i][0], acc[i][1], acc[i][2], acc[i][3] };   \
            float4 hi = { acc[i][4], acc[i][5], acc[i][6], acc[i][7] };   \
            r_[((i << 1) + 0) * 64 + lt] = lo;                            \
            r_[((i << 1) + 1) * 64 + lt] = hi;                            \
        } }
#define ADD_ACC(REG) {                                                    \
        float4* r_ = buf + ((REG) << 10);                                 \
        _Pragma("unroll")                                                 \
        for (int i = 0; i < 8; ++i) {                                     \
            float4 lo = r_[((i << 1) + 0) * 64 + lt];                     \
            float4 hi = r_[((i << 1) + 1) * 64 + lt];                     \
            acc[i][0] += lo.x; acc[i][1] += lo.y;                         \
            acc[i][2] += lo.z; acc[i][3] += lo.w;                         \
            acc[i][4] += hi.x; acc[i][5] += hi.y;                         \
            acc[i][6] += hi.z; acc[i][7] += hi.w;                         \
        } }

    __syncthreads();
    if (w >= 4) STORE_ACC(w - 4);
    __syncthreads();
    if (w < 4) ADD_ACC(w);
    __syncthreads();
    if (w == 2 || w == 3) STORE_ACC(w - 2);
    __syncthreads();
    if (w < 2) ADD_ACC(w);
    __syncthreads();
    if (w == 1) STORE_ACC(0);
    __syncthreads();
    if (w == 0) {
        ADD_ACC(0);
        float base = basep[0];
#pragma unroll
        for (int i = 0; i < 8; ++i) {
            float4 o0, o1;
            o0.x = __saturatef((acc[i][0] + base) * (1.0f / 6.0f) + 0.5f);
            o0.y = __saturatef((acc[i][1] + base) * (1.0f / 6.0f) + 0.5f);
            o0.z = __saturatef((acc[i][2] + base) * (1.0f / 6.0f) + 0.5f);
            o0.w = __saturatef((acc[i][3] + base) * (1.0f / 6.0f) + 0.5f);
            o1.x = __saturatef((acc[i][4] + base) * (1.0f / 6.0f) + 0.5f);
            o1.y = __saturatef((acc[i][5] + base) * (1.0f / 6.0f) + 0.5f);
            o1.z = __saturatef((acc[i][6] + base) * (1.0f / 6.0f) + 0.5f);
            o1.w = __saturatef((acc[i][7] + base) * (1.0f / 6.0f) + 0.5f);
            size_t orow = (size_t)(bi64 + ib + i) * 1024 + bj64 + jb;
            *(float4*)(out + orow) = o0;
            *(float4*)(out + orow + 4) = o1;
        }
    }
#undef STORE_ACC
#undef ADD_ACC
}

extern "C" void kernel_launch(void* const* d_in, const int* in_sizes, int n_in,
                              void* d_out, int out_size, void* d_ws, size_t ws_size,
                              hipStream_t stream) {
    const float* x     = (const float*)d_in[0];
    const float* W_enc = (const float*)d_in[1];
    const float* b_enc = (const float*)d_in[2];
    const float* W1    = (const float*)d_in[3];
    const float* b1    = (const float*)d_in[4];
    const float* W2    = (const float*)d_in[5];
    const float* b2    = (const float*)d_in[6];
    float* out = (float*)d_out;

    u32* ws = (u32*)d_ws;
    const int PLANE = 128 * 1024;          // u32 per f16 plane = 512 KB
    u32* PAa = ws;
    u32* PAe = ws + PLANE;
    u32* PBb = ws + 2 * PLANE;
    u32* PBe = ws + 3 * PLANE;
    u32* W2m = ws + 4 * PLANE;
    u32* W2e = ws + 4 * PLANE + 128;
    float* basep = (float*)(ws + 4 * PLANE + 256);

    prep_kernel<<<257, 256, 0, stream>>>(x, W_enc, b_enc, W1, b1, W2, b2,
                                         PAa, PAe, PBb, PBe, W2m, W2e, basep);
    pair_kernel<<<256, 512, 0, stream>>>(PAa, PAe, PBb, PBe,
                                         W2m, W2e, basep, out);
}

// Round 16
// 104.780 us; speedup vs baseline: 1.3004x; 1.3004x over previous
//
#include <hip/hip_runtime.h>
#include <math.h>

// n=1024, raw=128, d=128, h=256
// prep (257 blocks): blocks 0..255: z = x@W_enc + b_enc (LDS);
//   a' = (z@W1[:d])*log2e; b' = (z@W1[d:]+b1)*log2e; e=exp2(a'), f=exp2(b')
//   f16 half2 planes [k2][n] (k-paired via shfl_xor(1)):
//     PAa=half2{a'/64}, PAe=half2{e}, PBb=half2{b'/64}, PBe=half2{f}.
//   (1/64 prescale => |t'|/64 < 1, so max(t',0)/64 == clamp(a/64+b/64);
//    e*f>=0 so min(e*f,1)==clamp(e*f). VOP3P clamp bit fuses both.)
//   block 256: base = b2 - SELU_AS*sum(W2);
//     W2m[k2]=half2{64*S_OVER_L2E*w}, W2e[k2]=half2{SELU_AS*w}
// pair (grid 16x16, 512 thr): tile 64x64. Wave w = K-eighth, k2 in
//   [16w,16w+16), 2 sub-chunks of 8 k2 in a WAVE-PRIVATE 8 KB LDS region
//   (no staging barriers). 8x8 register tile/thread.
//   Hot loop: 4 instr/pair-k2: pk_add+clamp, pk_mul+clamp, 2x fdot2.
//   3-round LDS tree-reduction over K-eighths; wave 0 writes hsig.
// This is the R12 structure — empirical optimum across R9..R15 variants.

#define LOG2E       1.4426950408889634f
#define SELU_AS     1.7580993408473766f   // scale*alpha
#define S_OVER_L2E  0.7282921587620419f   // scale/log2e
#define INV64       0.015625f

typedef float v2f __attribute__((ext_vector_type(2)));
typedef _Float16 v2h __attribute__((ext_vector_type(2)));
typedef unsigned int u32;

__global__ __launch_bounds__(256) void prep_kernel(
    const float* __restrict__ x, const float* __restrict__ W_enc,
    const float* __restrict__ b_enc, const float* __restrict__ W1,
    const float* __restrict__ b1, const float* __restrict__ W2,
    const float* __restrict__ b2, u32* __restrict__ PAa,
    u32* __restrict__ PAe, u32* __restrict__ PBb, u32* __restrict__ PBe,
    u32* __restrict__ W2m, u32* __restrict__ W2e, float* __restrict__ basep)
{
    __shared__ float zs[512];
    int t = threadIdx.x, b = blockIdx.x;
    if (b < 256) {
        int r0 = b << 2;
        int r = t >> 6;                   // wave-uniform row 0..3
        int dd = (t & 63) << 1;
        const float* xr = x + (size_t)(r0 + r) * 128;
        v2f z = { b_enc[dd], b_enc[dd + 1] };
#pragma unroll 8
        for (int dl = 0; dl < 128; ++dl) {
            float xv = xr[dl];
            v2f xx = { xv, xv };
            v2f wv = *(const v2f*)(W_enc + (size_t)dl * 128 + dd);
            z = __builtin_elementwise_fma(xx, wv, z);
        }
        zs[r * 128 + dd] = z.x;
        zs[r * 128 + dd + 1] = z.y;
        __syncthreads();

        int c = t;                        // h-column (= k) 0..255
        float b1c = b1[c];
        float accA0 = 0.f, accA1 = 0.f, accA2 = 0.f, accA3 = 0.f;
        float accB0 = b1c, accB1 = b1c, accB2 = b1c, accB3 = b1c;
        const float* w1a = W1 + c;
        const float* w1b = W1 + 128 * 256 + c;
#pragma unroll 4
        for (int dl = 0; dl < 128; ++dl) {
            float wa = w1a[(size_t)dl * 256];
            float wb = w1b[(size_t)dl * 256];
            float z0 = zs[dl], z1 = zs[128 + dl], z2 = zs[256 + dl], z3 = zs[384 + dl];
            accA0 = fmaf(z0, wa, accA0); accB0 = fmaf(z0, wb, accB0);
            accA1 = fmaf(z1, wa, accA1); accB1 = fmaf(z1, wb, accB1);
            accA2 = fmaf(z2, wa, accA2); accB2 = fmaf(z2, wb, accB2);
            accA3 = fmaf(z3, wa, accA3); accB3 = fmaf(z3, wb, accB3);
        }
        float ar[4] = { accA0 * LOG2E, accA1 * LOG2E, accA2 * LOG2E, accA3 * LOG2E };
        float br[4] = { accB0 * LOG2E, accB1 * LOG2E, accB2 * LOG2E, accB3 * LOG2E };
        u32 pa[4], pe[4], pb[4], pf[4];
        bool odd = (c & 1);
#pragma unroll
        for (int r2 = 0; r2 < 4; ++r2) {
            float er = __builtin_amdgcn_exp2f(ar[r2]);
            float fr = __builtin_amdgcn_exp2f(br[r2]);
            float aN = __shfl_xor(ar[r2], 1);
            float eN = __shfl_xor(er, 1);
            float bN = __shfl_xor(br[r2], 1);
            float fN = __shfl_xor(fr, 1);
            pa[r2] = __builtin_bit_cast(u32,
                __builtin_amdgcn_cvt_pkrtz(ar[r2] * INV64, aN * INV64));
            pe[r2] = __builtin_bit_cast(u32, __builtin_amdgcn_cvt_pkrtz(er, eN));
            pb[r2] = __builtin_bit_cast(u32,
                __builtin_amdgcn_cvt_pkrtz(bN * INV64, br[r2] * INV64));
            pf[r2] = __builtin_bit_cast(u32, __builtin_amdgcn_cvt_pkrtz(fN, fr));
        }
        size_t o = (size_t)(c >> 1) * 1024 + r0;    // [k2][n]
        if (!odd) {
            *(uint4*)(PAa + o) = make_uint4(pa[0], pa[1], pa[2], pa[3]);
            *(uint4*)(PAe + o) = make_uint4(pe[0], pe[1], pe[2], pe[3]);
        } else {
            *(uint4*)(PBb + o) = make_uint4(pb[0], pb[1], pb[2], pb[3]);
            *(uint4*)(PBe + o) = make_uint4(pf[0], pf[1], pf[2], pf[3]);
        }
    } else {
        if (t < 128) {
            float w0 = W2[2 * t], w1 = W2[2 * t + 1];
            const float S64 = S_OVER_L2E * 64.0f;
            W2m[t] = __builtin_bit_cast(u32,
                __builtin_amdgcn_cvt_pkrtz(S64 * w0, S64 * w1));
            W2e[t] = __builtin_bit_cast(u32,
                __builtin_amdgcn_cvt_pkrtz(SELU_AS * w0, SELU_AS * w1));
        }
        if (t < 64) {
            float s = W2[t] + W2[t + 64] + W2[t + 128] + W2[t + 192];
#pragma unroll
            for (int o = 32; o > 0; o >>= 1) s += __shfl_down(s, o);
            if (t == 0) basep[0] = fmaf(-SELU_AS, s, b2[0]);
        }
    }
}

__device__ __forceinline__ v2h clamp2(v2h v) {
    const v2h z = { (_Float16)0.f, (_Float16)0.f };
    const v2h o = { (_Float16)1.f, (_Float16)1.f };
    // minnum(maxnum(x,0),1) -> VOP3P clamp bit on the producing instruction
    return __builtin_elementwise_min(__builtin_elementwise_max(v, z), o);
}

// grid (16,16), 512 threads = 8 waves. Wave w covers k2 in [16w,16w+16)
// via 2 sub-chunks of 8 k2 in its PRIVATE 8 KB LDS region (no barriers
// during compute). Per-thread 8x8 register tile; tree-reduce at the end.
__global__ __launch_bounds__(512, 2) void pair_kernel(
    const u32* __restrict__ PAa, const u32* __restrict__ PAe,
    const u32* __restrict__ PBb, const u32* __restrict__ PBe,
    const u32* __restrict__ W2m, const u32* __restrict__ W2e,
    const float* __restrict__ basep, float* __restrict__ out)
{
    __shared__ __align__(16) u32 S[16384];   // 64 KB

    int t = threadIdx.x;
    int w = t >> 6;                 // wave / K-eighth 0..7
    int lt = t & 63;
    int bj64 = blockIdx.x << 6, bi64 = blockIdx.y << 6;
    int jb = (lt & 7) << 3;         // j base 0..56
    int ib = (lt >> 3) << 3;        // i base 0..56

    u32* Q  = S + (w << 11);        // 2048 u32 = 8 KB, wave-private
    u32* Aa = Q;                    // [8 k2][64]
    u32* Ae = Q + 512;
    u32* Bb = Q + 1024;
    u32* Be = Q + 1536;

    float acc[8][8];
#pragma unroll
    for (int i = 0; i < 8; ++i)
#pragma unroll
        for (int j = 0; j < 8; ++j) acc[i][j] = 0.f;

    for (int sc = 0; sc < 2; ++sc) {
        int k2base = (w << 4) + (sc << 3);
        asm volatile("" ::: "memory");       // keep stage writes after prior reads
#pragma unroll
        for (int p = 0; p < 2; ++p) {
            int idx = (p << 6) + lt;         // 0..127
            int row = idx >> 4;
            int col = (idx & 15) << 2;
            size_t go = (size_t)(k2base + row) * 1024;
            *(uint4*)&Aa[idx << 2] = *(const uint4*)(PAa + go + bj64 + col);
            *(uint4*)&Ae[idx << 2] = *(const uint4*)(PAe + go + bj64 + col);
            *(uint4*)&Bb[idx << 2] = *(const uint4*)(PBb + go + bi64 + col);
            *(uint4*)&Be[idx << 2] = *(const uint4*)(PBe + go + bi64 + col);
        }
        asm volatile("s_waitcnt lgkmcnt(0)" ::: "memory");  // wave-private: no barrier

        const u32* Wm = W2m + k2base;
        const u32* We = W2e + k2base;
#pragma unroll 4
        for (int k2 = 0; k2 < 8; ++k2) {
            v2h w2m = __builtin_bit_cast(v2h, Wm[k2]);       // uniform -> s_load
            v2h w2e = __builtin_bit_cast(v2h, We[k2]);
            uint4 qa0 = *(const uint4*)&Aa[(k2 << 6) + jb];
            uint4 qa1 = *(const uint4*)&Aa[(k2 << 6) + jb + 4];
            uint4 qe0 = *(const uint4*)&Ae[(k2 << 6) + jb];
            uint4 qe1 = *(const uint4*)&Ae[(k2 << 6) + jb + 4];
            uint4 qb0 = *(const uint4*)&Bb[(k2 << 6) + ib];
            uint4 qb1 = *(const uint4*)&Bb[(k2 << 6) + ib + 4];
            uint4 qf0 = *(const uint4*)&Be[(k2 << 6) + ib];
            uint4 qf1 = *(const uint4*)&Be[(k2 << 6) + ib + 4];
            v2h A[8] = { __builtin_bit_cast(v2h, qa0.x), __builtin_bit_cast(v2h, qa0.y),
                         __builtin_bit_cast(v2h, qa0.z), __builtin_bit_cast(v2h, qa0.w),
                         __builtin_bit_cast(v2h, qa1.x), __builtin_bit_cast(v2h, qa1.y),
                         __builtin_bit_cast(v2h, qa1.z), __builtin_bit_cast(v2h, qa1.w) };
            v2h E[8] = { __builtin_bit_cast(v2h, qe0.x), __builtin_bit_cast(v2h, qe0.y),
                         __builtin_bit_cast(v2h, qe0.z), __builtin_bit_cast(v2h, qe0.w),
                         __builtin_bit_cast(v2h, qe1.x), __builtin_bit_cast(v2h, qe1.y),
                         __builtin_bit_cast(v2h, qe1.z), __builtin_bit_cast(v2h, qe1.w) };
            v2h B[8] = { __builtin_bit_cast(v2h, qb0.x), __builtin_bit_cast(v2h, qb0.y),
                         __builtin_bit_cast(v2h, qb0.z), __builtin_bit_cast(v2h, qb0.w),
                         __builtin_bit_cast(v2h, qb1.x), __builtin_bit_cast(v2h, qb1.y),
                         __builtin_bit_cast(v2h, qb1.z), __builtin_bit_cast(v2h, qb1.w) };
            v2h F[8] = { __builtin_bit_cast(v2h, qf0.x), __builtin_bit_cast(v2h, qf0.y),
                         __builtin_bit_cast(v2h, qf0.z), __builtin_bit_cast(v2h, qf0.w),
                         __builtin_bit_cast(v2h, qf1.x), __builtin_bit_cast(v2h, qf1.y),
                         __builtin_bit_cast(v2h, qf1.z), __builtin_bit_cast(v2h, qf1.w) };
#pragma unroll
            for (int i = 0; i < 8; ++i) {
#pragma unroll
                for (int j = 0; j < 8; ++j) {
                    v2h t2 = clamp2(A[j] + B[i]);   // pk_add_f16 + clamp bit
                    v2h p2 = clamp2(E[j] * F[i]);   // pk_mul_f16 + clamp bit
                    acc[i][j] = __builtin_amdgcn_fdot2(t2, w2m, acc[i][j], false);
                    acc[i][j] = __builtin_amdgcn_fdot2(p2, w2e, acc[i][j], false);
                }
            }
        }
    }

    // ---- tree reduction over the 8 K-eighths (regions: 16 KB each) ----
    float4* buf = (float4*)S;
#define STORE_ACC(REG) {                                                  \
        float4* r_ = buf + ((REG) << 10);                                 \
        _Pragma("unroll")                                                 \
        for (int i = 0; i < 8; ++i) {                                     \
            float4 lo = { acc[i][0], acc[i][1], acc[i][2], acc[i][3] };   \
            float4 hi = { acc[i][4], acc[i][5], acc[i][6], acc[i][7] };   \
            r_[((i << 1) + 0) * 64 + lt] = lo;                            \
            r_[((i << 1) + 1) * 64 + lt] = hi;                            \
        } }
#define ADD_ACC(REG) {                                                    \
        float4* r_ = buf + ((REG) << 10);                                 \
        _Pragma("unroll")                                                 \
        for (int i = 0; i < 8; ++i) {                                     \
            float4 lo = r_[((i << 1) + 0) * 64 + lt];                     \
            float4 hi = r_[((i << 1) + 1) * 64 + lt];                     \
            acc[i][0] += lo.x; acc[i][1] += lo.y;                         \
            acc[i][2] += lo.z; acc[i][3] += lo.w;                         \
            acc[i][4] += hi.x; acc[i][5] += hi.y;                         \
            acc[i][6] += hi.z; acc[i][7] += hi.w;                         \
        } }

    __syncthreads();
    if (w >= 4) STORE_ACC(w - 4);
    __syncthreads();
    if (w < 4) ADD_ACC(w);
    __syncthreads();
    if (w == 2 || w == 3) STORE_ACC(w - 2);
    __syncthreads();
    if (w < 2) ADD_ACC(w);
    __syncthreads();
    if (w == 1) STORE_ACC(0);
    __syncthreads();
    if (w == 0) {
        ADD_ACC(0);
        float base = basep[0];
#pragma unroll
        for (int i = 0; i < 8; ++i) {
            float4 o0, o1;
            o0.x = __saturatef((acc[i][0] + base) * (1.0f / 6.0f) + 0.5f);
            o0.y = __saturatef((acc[i][1] + base) * (1.0f / 6.0f) + 0.5f);
            o0.z = __saturatef((acc[i][2] + base) * (1.0f / 6.0f) + 0.5f);
            o0.w = __saturatef((acc[i][3] + base) * (1.0f / 6.0f) + 0.5f);
            o1.x = __saturatef((acc[i][4] + base) * (1.0f / 6.0f) + 0.5f);
            o1.y = __saturatef((acc[i][5] + base) * (1.0f / 6.0f) + 0.5f);
            o1.z = __saturatef((acc[i][6] + base) * (1.0f / 6.0f) + 0.5f);
            o1.w = __saturatef((acc[i][7] + base) * (1.0f / 6.0f) + 0.5f);
            size_t orow = (size_t)(bi64 + ib + i) * 1024 + bj64 + jb;
            *(float4*)(out + orow) = o0;
            *(float4*)(out + orow + 4) = o1;
        }
    }
#undef STORE_ACC
#undef ADD_ACC
}

extern "C" void kernel_launch(void* const* d_in, const int* in_sizes, int n_in,
                              void* d_out, int out_size, void* d_ws, size_t ws_size,
                              hipStream_t stream) {
    const float* x     = (const float*)d_in[0];
    const float* W_enc = (const float*)d_in[1];
    const float* b_enc = (const float*)d_in[2];
    const float* W1    = (const float*)d_in[3];
    const float* b1    = (const float*)d_in[4];
    const float* W2    = (const float*)d_in[5];
    const float* b2    = (const float*)d_in[6];
    float* out = (float*)d_out;

    u32* ws = (u32*)d_ws;
    const int PLANE = 128 * 1024;          // u32 per f16 plane = 512 KB
    u32* PAa = ws;
    u32* PAe = ws + PLANE;
    u32* PBb = ws + 2 * PLANE;
    u32* PBe = ws + 3 * PLANE;
    u32* W2m = ws + 4 * PLANE;
    u32* W2e = ws + 4 * PLANE + 128;
    float* basep = (float*)(ws + 4 * PLANE + 256);

    prep_kernel<<<257, 256, 0, stream>>>(x, W_enc, b_enc, W1, b1, W2, b2,
                                         PAa, PAe, PBb, PBe, W2m, W2e, basep);
    pair_kernel<<<dim3(16, 16), 512, 0, stream>>>(PAa, PAe, PBb, PBe,
                                                  W2m, W2e, basep, out);
}